// Round 21
// baseline (114.385 us; speedup 1.0000x reference)
//
#include <hip/hip_runtime.h>

// ---------------------------------------------------------------------------
// DWT autoencoder round trip. Level-2 dwt2+idwt2 cancel exactly -> LL1r==LL1.
//   K0:  weight reorder (verified layouts)
//   K1a: PURE STREAMING dwt: x -> 9 band planes (into d_out as scratch!) +
//        LL1. No LDS, no barriers, no halo (band rows use disjoint x rows),
//        float4 loads / float2 stores, all coalesced. ~200MB => ~32us floor.
//   K1b: R18's verified conv kernel with the stage reduced to a pure copy
//        (global bands -> LDS), one barrier, og-split conv.
//   K2:  convT4x4 s2 + idwt2 -> out (overwrites the band scratch; bands are
//        dead after K1b, kernels serialize on the stream).
// B=32, C=3, H=W=512.
// R20 lesson: paired ds_reads slightly worse -> LDS-issue falsified. k1's
// remaining overhead is band-math+loads entangled with conv in one kernel;
// this round separates streaming work from conv work (k2's proven shape).
// ---------------------------------------------------------------------------

#define BB 32

// K0: wd[(cin*9 + a*3 + q)*9 + o] = 0.5 * dw[o, cin, a, q]   (cin = ch*3+band)
//     wu[((cin*4+rt*2+ct)*4+di*2+dj)*9+o] = uw[cin, o, 3-di-2rt, 3-dj-2ct]
__global__ __launch_bounds__(256) void k0_rearrange(
    const float* __restrict__ dw, const float* __restrict__ uw,
    float* __restrict__ wd, float* __restrict__ wu)
{
    const int t = threadIdx.x;
    for (int i = t; i < 729; i += 256) {
        const int o   = i % 9;
        const int q   = (i / 9) % 3;
        const int a   = (i / 27) % 3;
        const int cin = i / 81;
        wd[i] = 0.5f * dw[o * 81 + cin * 9 + a * 3 + q];
    }
    for (int i = t; i < 1296; i += 256) {
        const int o = i % 9; int r = i / 9;
        const int dj = r & 1; const int di = (r >> 1) & 1; r >>= 2;
        const int ct = r & 1; const int rt = (r >> 1) & 1; const int cin = r >> 2;
        wu[i] = uw[cin * 144 + o * 16 + (3 - di - 2 * rt) * 4 + (3 - dj - 2 * ct)];
    }
}

// K1a: block = 2 band rows of one (b,ch). Thread t: row = 2*r2 + (t>>7),
// band cols {2s, 2s+1} with s = t&127. 2x float4 x loads (disjoint rows
// across threads -> each x byte read exactly once), 3 float2 band stores
// (planes ch*3+{0,1,2} of bd) + 1 float2 LL1 store. All coalesced.
__global__ __launch_bounds__(256) void k1a_bands(
    const float* __restrict__ x,     // (B,3,512,512)
    float* __restrict__ bd,          // (B,9,256,256) band planes (scratch)
    float* __restrict__ LL1)         // (B,3,256,256)
{
    const int t   = threadIdx.x;
    const int bid = blockIdx.x;                      // 0..12287
    const int swz = (bid & 7) * 1536 + (bid >> 3);   // XCD-contiguous chunks
    const int bc  = swz >> 7;                        // b*3+ch, 0..95
    const int r2  = swz & 127;                       // row pair 0..127
    const int row = 2 * r2 + (t >> 7);               // band row 0..255
    const int s   = t & 127;                         // col pair 0..127

    const float* xp = x + (((size_t)bc * 512 + 2 * row) * 512) + 4 * s;
    const float4 A  = *reinterpret_cast<const float4*>(xp);
    const float4 Bv = *reinterpret_cast<const float4*>(xp + 512);

    float2 lh, hl, hh, ll;
    {
        const float s0 = A.x + A.y, d0 = A.x - A.y;
        const float s1 = Bv.x + Bv.y, d1 = Bv.x - Bv.y;
        lh.x = s0 - s1; hl.x = d0 + d1; hh.x = d0 - d1; ll.x = (s0 + s1) * 0.5f;
    }
    {
        const float s0 = A.z + A.w, d0 = A.z - A.w;
        const float s1 = Bv.z + Bv.w, d1 = Bv.z - Bv.w;
        lh.y = s0 - s1; hl.y = d0 + d1; hh.y = d0 - d1; ll.y = (s0 + s1) * 0.5f;
    }

    const int b  = bc / 3;
    const int ch = bc - 3 * b;
    float* base = bd + ((((size_t)b * 9 + ch * 3) * 256 + row) * 256) + 2 * s;
    *reinterpret_cast<float2*>(base)           = lh;   // plane ch*3+0
    *reinterpret_cast<float2*>(base + 65536)   = hl;   // plane ch*3+1
    *reinterpret_cast<float2*>(base + 131072)  = hh;   // plane ch*3+2
    *reinterpret_cast<float2*>(
        LL1 + (((size_t)bc * 256 + row) * 256) + 2 * s) = ll;
}

// K1b: block = 8x16 y-tile. Stage = pure copy: 5049 items (9 planes x 17x33
// halo) global->LDS with zero for rB/cB < 0. One barrier. og-split conv
// (R18 verified): og=0 -> outputs 0-4, og=1 -> 5-8.
__global__ __launch_bounds__(256) void k1b_conv(
    const float* __restrict__ bd,    // (B,9,256,256) band planes
    const float* __restrict__ wd,    // reordered (cin,a,q,o), x0.5 folded
    const float* __restrict__ db,    // (9)
    float* __restrict__ y)           // (B,9,128,128)
{
    __shared__ float bnd[9 * 561];   // plane: 17 x 33, 20.2 KB

    const int t   = threadIdx.x;
    const int bid = blockIdx.x;                     // 0..4095
    const int swz = (bid & 7) * 512 + (bid >> 3);   // XCD-contiguous chunks
    const int b   = swz >> 7;                       // image 0..31
    const int tin = swz & 127;
    const int I0  = (tin >> 3) * 8;                 // y row origin (0..120)
    const int J0  = (tin & 7) * 16;                 // y col origin (0..112)

    // ---- stage: pure copy (coalesced over lc) ----
    for (int it = t; it < 5049; it += 256) {
        const int p  = it / 561;
        const int rc = it - p * 561;
        const int lr = rc / 33;                     // 0..16
        const int lc = rc - lr * 33;                // 0..32
        const int rB = 2 * I0 - 1 + lr;             // -1..254
        const int cB = 2 * J0 - 1 + lc;             // -1..254
        float v = 0.f;
        if (rB >= 0 && cB >= 0)
            v = bd[(((size_t)b * 9 + p) * 256 + rB) * 256 + cB];
        bnd[p * 561 + lr * 33 + lc] = v;
    }
    __syncthreads();

    // ---- conv: R18's verified og-split ----
    const int og = t >> 7;           // wave-uniform output half
    const int tl = t & 127;
    const int ti = tl >> 4;          // 0..7
    const int tj = tl & 15;          // 0..15
    const int I  = I0 + ti;
    const int J  = J0 + tj;

    if (og == 0) {
        float acc[5];
#pragma unroll
        for (int o = 0; o < 5; ++o) acc[o] = db[o];
        for (int cin = 0; cin < 9; ++cin) {
            float v[3][3];
#pragma unroll
            for (int a = 0; a < 3; ++a)
#pragma unroll
                for (int q = 0; q < 3; ++q)
                    v[a][q] = bnd[cin * 561 + (2 * ti + a) * 33 + 2 * tj + q];
            const float* wc = wd + cin * 81;
#pragma unroll
            for (int a = 0; a < 3; ++a)
#pragma unroll
                for (int q = 0; q < 3; ++q) {
                    const float vv = v[a][q];
                    const float* w9 = wc + (a * 3 + q) * 9;
#pragma unroll
                    for (int o = 0; o < 5; ++o) acc[o] += vv * w9[o];
                }
        }
#pragma unroll
        for (int o = 0; o < 5; ++o)
            y[(((size_t)b * 9 + o) * 128 + I) * 128 + J] = acc[o];
    } else {
        float acc[4];
#pragma unroll
        for (int o = 0; o < 4; ++o) acc[o] = db[5 + o];
        for (int cin = 0; cin < 9; ++cin) {
            float v[3][3];
#pragma unroll
            for (int a = 0; a < 3; ++a)
#pragma unroll
                for (int q = 0; q < 3; ++q)
                    v[a][q] = bnd[cin * 561 + (2 * ti + a) * 33 + 2 * tj + q];
            const float* wc = wd + cin * 81;
#pragma unroll
            for (int a = 0; a < 3; ++a)
#pragma unroll
                for (int q = 0; q < 3; ++q) {
                    const float vv = v[a][q];
                    const float* w9 = wc + (a * 3 + q) * 9 + 5;
#pragma unroll
                    for (int o = 0; o < 4; ++o) acc[o] += vv * w9[o];
                }
        }
#pragma unroll
        for (int o = 0; o < 4; ++o)
            y[(((size_t)b * 9 + 5 + o) * 128 + I) * 128 + J] = acc[o];
    }
}

// K2: unchanged verified kernel (overwrites d_out; bands are dead by now).
__global__ __launch_bounds__(256, 4) void k2_up_idwt(
    const float* __restrict__ yg,    // (B,9,128,128)
    const float* __restrict__ wu,    // reordered (cin,rt,ct,di,dj,o)
    const float* __restrict__ ub,    // (9)
    const float* __restrict__ LL1,   // (B,3,256,256)
    float* __restrict__ out)         // (B,3,512,512)
{
    __shared__ float ysh[9][18][19];

    const int t    = threadIdx.x;
    const int b    = blockIdx.x >> 6;
    const int tile = blockIdx.x & 63;
    const int r0   = (tile >> 3) << 5;  // 256-res tile origin
    const int c0   = (tile & 7) << 5;
    const int p0   = (r0 >> 1) - 1;     // y row of local 0
    const int q0   = (c0 >> 1) - 1;

    for (int item = t; item < 9 * 324; item += 256) {
        const int cin = item / 324;
        int rem       = item - cin * 324;
        const int lp  = rem / 18;
        const int lq  = rem - lp * 18;
        const int p   = p0 + lp, q = q0 + lq;
        float v = 0.f;
        if (p >= 0 && p < 128 && q >= 0 && q < 128)
            v = yg[(((size_t)b * 9 + cin) * 128 + p) * 128 + q];
        ysh[cin][lp][lq] = v;
    }
    __syncthreads();

    const int i2 = t >> 4;   // 0..15
    const int j2 = t & 15;   // 0..15

    float acc[2][2][9];      // [di][dj][out-ch]
#pragma unroll
    for (int di = 0; di < 2; ++di)
#pragma unroll
        for (int dj = 0; dj < 2; ++dj)
#pragma unroll
            for (int o = 0; o < 9; ++o) acc[di][dj][o] = ub[o];

    for (int cin = 0; cin < 9; ++cin) {
        float yv[3][3];
#pragma unroll
        for (int r = 0; r < 3; ++r)
#pragma unroll
            for (int c = 0; c < 3; ++c)
                yv[r][c] = ysh[cin][i2 + r][j2 + c];
        const float* wc = wu + cin * 144;
#pragma unroll
        for (int rt = 0; rt < 2; ++rt)
#pragma unroll
            for (int ct = 0; ct < 2; ++ct) {
                const float* wg = wc + (rt * 2 + ct) * 36;  // 36 consecutive
#pragma unroll
                for (int di = 0; di < 2; ++di)
#pragma unroll
                    for (int dj = 0; dj < 2; ++dj) {
                        const float vv = yv[di + rt][dj + ct];
                        const float* w9 = wg + (di * 2 + dj) * 9;
#pragma unroll
                        for (int o = 0; o < 9; ++o)
                            acc[di][dj][o] += vv * w9[o];
                    }
            }
    }

#pragma unroll
    for (int cc = 0; cc < 3; ++cc) {
#pragma unroll
        for (int di = 0; di < 2; ++di) {
            const int I = r0 + 2 * i2 + di;
            const int J = c0 + 2 * j2;
            const float2 llv = *reinterpret_cast<const float2*>(
                LL1 + (((size_t)b * 3 + cc) * 256 + I) * 256 + J);
            float4 top, bot;
            {
                const float ll = llv.x;
                const float lh = acc[di][0][cc * 3 + 0];
                const float hl = acc[di][0][cc * 3 + 1];
                const float hh = acc[di][0][cc * 3 + 2];
                const float e0 = ll + lh, od0 = ll - lh;
                const float e1 = hl + hh, od1 = hl - hh;
                top.x = (e0 + e1) * 0.5f; top.y = (e0 - e1) * 0.5f;
                bot.x = (od0 + od1) * 0.5f; bot.y = (od0 - od1) * 0.5f;
            }
            {
                const float ll = llv.y;
                const float lh = acc[di][1][cc * 3 + 0];
                const float hl = acc[di][1][cc * 3 + 1];
                const float hh = acc[di][1][cc * 3 + 2];
                const float e0 = ll + lh, od0 = ll - lh;
                const float e1 = hl + hh, od1 = hl - hh;
                top.z = (e0 + e1) * 0.5f; top.w = (e0 - e1) * 0.5f;
                bot.z = (od0 + od1) * 0.5f; bot.w = (od0 - od1) * 0.5f;
            }
            float* op = out + (((size_t)b * 3 + cc) * 512 + 2 * I) * 512 + 2 * J;
            *reinterpret_cast<float4*>(op) = top;
            *reinterpret_cast<float4*>(op + 512) = bot;
        }
    }
}

extern "C" void kernel_launch(void* const* d_in, const int* in_sizes, int n_in,
                              void* d_out, int out_size, void* d_ws, size_t ws_size,
                              hipStream_t stream) {
    const float* x  = (const float*)d_in[0];
    const float* dw = (const float*)d_in[1];
    const float* db = (const float*)d_in[2];
    const float* uw = (const float*)d_in[3];
    const float* ub = (const float*)d_in[4];
    float* outp = (float*)d_out;

    float* wsf = (float*)d_ws;
    float* wd  = wsf;            // 729 floats (pad to 768)
    float* wu  = wsf + 768;      // 1296 floats
    float* LL1 = wsf + 2304;                         // 25.2 MB
    float* y   = LL1 + (size_t)BB * 3 * 256 * 256;   // 18.9 MB
    float* bd  = outp;           // band planes live in d_out (dead before K2)

    k0_rearrange<<<dim3(1), dim3(256), 0, stream>>>(dw, uw, wd, wu);
    k1a_bands<<<dim3(12288), dim3(256), 0, stream>>>(x, bd, LL1);
    k1b_conv<<<dim3(4096), dim3(256), 0, stream>>>(bd, wd, db, y);
    k2_up_idwt<<<dim3(BB * 64), dim3(256), 0, stream>>>(y, wu, ub, LL1, outp);
}

// Round 22
// 82.311 us; speedup vs baseline: 1.3897x; 1.3897x over previous
//
#include <hip/hip_runtime.h>

// ---------------------------------------------------------------------------
// DWT autoencoder round trip. Level-2 dwt2+idwt2 cancel exactly -> LL1r==LL1.
// FINAL CONFIG = R14 (best measured: 82.2us). 16 alternative k1 structures
// (staging mechanism, barriers, occupancy 19->73%, VMEM width/count, LDS-read
// count, weight paths, register blocking, fusion, decomposition) all measured
// worse or equal; k1 is pinned at ~60us on an unexplained latency wall, k2
// runs at its memory roofline.
//   K0: rearrange conv weights into consumption order + zero-page
//   K1: WAVE-INDEPENDENT dwt+conv. One wave = one 4x16 y-tile; stages its
//       own x rows via gload_lds (15 per wave, 14.7KB), wave-local
//       s_waitcnt vmcnt(0), no __syncthreads; verified band+conv math.
//   K2: convT4x4 s2 of y -> l1 bands, fused with idwt2(LL1, l1) -> out
// B=32, C=3, H=W=512.
// ---------------------------------------------------------------------------

#define BB 32

// K0: wd[((ch*3+a)*3+q)*27 + band*9 + o] = 0.5 * dw[o, ch*3+band, a, q]
//     wu[((cin*4+rt*2+ct)*4+di*2+dj)*9+o] = uw[cin, o, 3-di-2rt, 3-dj-2ct]
//     zp[0..15] = 0 (zero-page for invalid gload lanes)
__global__ __launch_bounds__(256) void k0_rearrange(
    const float* __restrict__ dw, const float* __restrict__ uw,
    float* __restrict__ wd, float* __restrict__ wu, float* __restrict__ zp)
{
    const int t = threadIdx.x;
    for (int i = t; i < 729; i += 256) {
        const int o    = i % 9;
        const int band = (i / 9) % 3;
        const int q    = (i / 27) % 3;
        const int a    = (i / 81) % 3;
        const int ch   = i / 243;
        wd[i] = 0.5f * dw[o * 81 + (ch * 3 + band) * 9 + a * 3 + q];
    }
    for (int i = t; i < 1296; i += 256) {
        const int o = i % 9; int r = i / 9;
        const int dj = r & 1; const int di = (r >> 1) & 1; r >>= 2;
        const int ct = r & 1; const int rt = (r >> 1) & 1; const int cin = r >> 2;
        wu[i] = uw[cin * 144 + o * 16 + (3 - di - 2 * rt) * 4 + (3 - dj - 2 * ct)];
    }
    if (t < 16) zp[t] = 0.f;
}

__device__ __forceinline__ void gload16(const float* gp, float* lp) {
    __builtin_amdgcn_global_load_lds(
        (const __attribute__((address_space(1))) void*)gp,
        (__attribute__((address_space(3))) void*)lp, 16, 0, 0);
}

// K1: one wave (64 threads) = one 4x16 y-tile. x tile per ch = 18 rows x
// 17 float4 = 306 slots, padded to 320 (5 full-wave gload rounds; invalid
// lanes read the zero-page, junk lands in pad slots never read).
// Lane: ti = lane>>4 (0..3), tj = lane&15. No barriers.
__global__ __launch_bounds__(64) void k1_dwt_down(
    const float* __restrict__ x,     // (B,3,512,512)
    const float* __restrict__ wd,    // reordered (ch,a,q,band,o), x0.5 folded
    const float* __restrict__ db,    // (9)
    const float* __restrict__ zp,    // 16-float zero page
    float* __restrict__ LL1,         // (B,3,256,256)
    float* __restrict__ y)           // (B,9,128,128)
{
    __shared__ float xs[3 * 1280];   // 3 ch x 320 f4 slots = 15.36 KB

    const int lane = threadIdx.x;
    const int bid  = blockIdx.x;                      // 0..8191
    const int swz  = (bid & 7) * 1024 + (bid >> 3);   // XCD-contiguous chunks
    const int b    = swz >> 8;                        // image 0..31
    const int tin  = swz & 255;                       // tile within image
    const int I0   = (tin >> 3) * 4;                  // y row origin (0..124)
    const int J0   = (tin & 7) * 16;                  // y col origin (0..112)
    const int gr0  = 4 * I0 - 2;                      // x row of LDS row 0
    const int gc0  = 4 * J0 - 4;                      // x col of LDS col 0

    // ---- stage: 3 ch x 5 full-wave gload rounds (this wave's rows only) ----
#pragma unroll
    for (int ch = 0; ch < 3; ++ch) {
        const float* xc = x + ((size_t)b * 3 + ch) * (512 * 512);
#pragma unroll
        for (int n = 0; n < 5; ++n) {
            const int idx = n * 64 + lane;    // slot within channel, 0..319
            const int lr  = idx / 17;         // 0..18 (306 used -> lr<=17)
            const int f4c = idx - lr * 17;
            const int gr  = gr0 + lr;
            const bool ok = (idx < 306) && (gr >= 0) && !(f4c == 0 && J0 == 0);
            const float* gp = ok ? (xc + (size_t)gr * 512 + gc0 + 4 * f4c) : zp;
            gload16(gp, &xs[(ch * 320 + idx) * 4]);
        }
    }

    float acc[9];
#pragma unroll
    for (int o = 0; o < 9; ++o) acc[o] = db[o];

    // wave-local drain: this wave's gloads are its own LDS producers
    asm volatile("s_waitcnt vmcnt(0)" ::: "memory");
    __builtin_amdgcn_sched_barrier(0);

    const int ti = lane >> 4;        // 0..3
    const int tj = lane & 15;        // 0..15
    const int I  = I0 + ti;
    const int J  = J0 + tj;

#pragma unroll
    for (int ch = 0; ch < 3; ++ch) {
        const float* xb  = xs + ch * 1280;
        const float* wch = wd + ch * 243;
        float* llc = LL1 + ((size_t)b * 3 + ch) * (256 * 256);

#pragma unroll
        for (int a = 0; a < 3; ++a) {
            float2 p[2][3];                   // [x-row parity][band-col tap]
#pragma unroll
            for (int rr = 0; rr < 2; ++rr)
#pragma unroll
                for (int k = 0; k < 3; ++k)
                    p[rr][k] = *reinterpret_cast<const float2*>(
                        &xs[ch * 1280 + (4 * ti + 2 * a + rr) * 68 + 4 * tj + 2 + 2 * k]);

            float lh[3], hl[3], hh[3], llv1, llv2;
            {
                const float s0 = p[0][0].x + p[0][0].y, d0 = p[0][0].x - p[0][0].y;
                const float s1 = p[1][0].x + p[1][0].y, d1 = p[1][0].x - p[1][0].y;
                lh[0] = s0 - s1; hl[0] = d0 + d1; hh[0] = d0 - d1;
            }
            {
                const float s0 = p[0][1].x + p[0][1].y, d0 = p[0][1].x - p[0][1].y;
                const float s1 = p[1][1].x + p[1][1].y, d1 = p[1][1].x - p[1][1].y;
                lh[1] = s0 - s1; hl[1] = d0 + d1; hh[1] = d0 - d1;
                llv1 = (s0 + s1) * 0.5f;
            }
            {
                const float s0 = p[0][2].x + p[0][2].y, d0 = p[0][2].x - p[0][2].y;
                const float s1 = p[1][2].x + p[1][2].y, d1 = p[1][2].x - p[1][2].y;
                lh[2] = s0 - s1; hl[2] = d0 + d1; hh[2] = d0 - d1;
                llv2 = (s0 + s1) * 0.5f;
            }

            // LL1: level-1 row r=2I-1+a (a>=1), cols {2J, 2J+1}
            if (a >= 1) {
                float2 w2; w2.x = llv1; w2.y = llv2;
                *reinterpret_cast<float2*>(llc + (size_t)(2 * I - 1 + a) * 256 + 2 * J) = w2;
            }

            const float* wg = wch + a * 81;
#pragma unroll
            for (int q = 0; q < 3; ++q) {
                const float* w0 = wg + q * 27;   // 27 consecutive uniform weights
#pragma unroll
                for (int o = 0; o < 9; ++o) acc[o] += lh[q] * w0[o];
#pragma unroll
                for (int o = 0; o < 9; ++o) acc[o] += hl[q] * w0[9 + o];
#pragma unroll
                for (int o = 0; o < 9; ++o) acc[o] += hh[q] * w0[18 + o];
            }
        }
    }

#pragma unroll
    for (int o = 0; o < 9; ++o)
        y[(((size_t)b * 9 + o) * 128 + I) * 128 + J] = acc[o];
}

// K2: one block = one batch image, a 32x32 tile at 256-res (=> 64x64 output
// pixels at 512-res), all 3 colors. Each thread owns a 2x2 parity quad; all
// 36 accumulators live (needs VGPR room -> launch_bounds(256,4)).
__global__ __launch_bounds__(256, 4) void k2_up_idwt(
    const float* __restrict__ yg,    // (B,9,128,128)
    const float* __restrict__ wu,    // reordered (cin,rt,ct,di,dj,o)
    const float* __restrict__ ub,    // (9)
    const float* __restrict__ LL1,   // (B,3,256,256)
    float* __restrict__ out)         // (B,3,512,512)
{
    __shared__ float ysh[9][18][19];

    const int t    = threadIdx.x;
    const int b    = blockIdx.x >> 6;
    const int tile = blockIdx.x & 63;
    const int r0   = (tile >> 3) << 5;  // 256-res tile origin
    const int c0   = (tile & 7) << 5;
    const int p0   = (r0 >> 1) - 1;     // y row of local 0
    const int q0   = (c0 >> 1) - 1;

    // ---- stage y tile (18x18 halo, 9 ch) into LDS ----
    for (int item = t; item < 9 * 324; item += 256) {
        const int cin = item / 324;
        int rem       = item - cin * 324;
        const int lp  = rem / 18;
        const int lq  = rem - lp * 18;
        const int p   = p0 + lp, q = q0 + lq;
        float v = 0.f;
        if (p >= 0 && p < 128 && q >= 0 && q < 128)
            v = yg[(((size_t)b * 9 + cin) * 128 + p) * 128 + q];
        ysh[cin][lp][lq] = v;
    }
    __syncthreads();

    const int i2 = t >> 4;   // 0..15
    const int j2 = t & 15;   // 0..15

    float acc[2][2][9];      // [di][dj][out-ch]
#pragma unroll
    for (int di = 0; di < 2; ++di)
#pragma unroll
        for (int dj = 0; dj < 2; ++dj)
#pragma unroll
            for (int o = 0; o < 9; ++o) acc[di][dj][o] = ub[o];

    for (int cin = 0; cin < 9; ++cin) {
        float yv[3][3];
#pragma unroll
        for (int r = 0; r < 3; ++r)
#pragma unroll
            for (int c = 0; c < 3; ++c)
                yv[r][c] = ysh[cin][i2 + r][j2 + c];
        const float* wc = wu + cin * 144;
#pragma unroll
        for (int rt = 0; rt < 2; ++rt)
#pragma unroll
            for (int ct = 0; ct < 2; ++ct) {
                const float* wg = wc + (rt * 2 + ct) * 36;  // 36 consecutive
#pragma unroll
                for (int di = 0; di < 2; ++di)
#pragma unroll
                    for (int dj = 0; dj < 2; ++dj) {
                        const float vv = yv[di + rt][dj + ct];
                        const float* w9 = wg + (di * 2 + dj) * 9;
#pragma unroll
                        for (int o = 0; o < 9; ++o)
                            acc[di][dj][o] += vv * w9[o];
                    }
            }
    }

    // ---- epilogue: idwt2(LL1, LH, HL, HH) -> 4x4 output pixels / color ----
#pragma unroll
    for (int cc = 0; cc < 3; ++cc) {
#pragma unroll
        for (int di = 0; di < 2; ++di) {
            const int I = r0 + 2 * i2 + di;
            const int J = c0 + 2 * j2;
            const float2 llv = *reinterpret_cast<const float2*>(
                LL1 + (((size_t)b * 3 + cc) * 256 + I) * 256 + J);
            float4 top, bot;
            {
                const float ll = llv.x;
                const float lh = acc[di][0][cc * 3 + 0];
                const float hl = acc[di][0][cc * 3 + 1];
                const float hh = acc[di][0][cc * 3 + 2];
                const float e0 = ll + lh, od0 = ll - lh;
                const float e1 = hl + hh, od1 = hl - hh;
                top.x = (e0 + e1) * 0.5f; top.y = (e0 - e1) * 0.5f;
                bot.x = (od0 + od1) * 0.5f; bot.y = (od0 - od1) * 0.5f;
            }
            {
                const float ll = llv.y;
                const float lh = acc[di][1][cc * 3 + 0];
                const float hl = acc[di][1][cc * 3 + 1];
                const float hh = acc[di][1][cc * 3 + 2];
                const float e0 = ll + lh, od0 = ll - lh;
                const float e1 = hl + hh, od1 = hl - hh;
                top.z = (e0 + e1) * 0.5f; top.w = (e0 - e1) * 0.5f;
                bot.z = (od0 + od1) * 0.5f; bot.w = (od0 - od1) * 0.5f;
            }
            float* op = out + (((size_t)b * 3 + cc) * 512 + 2 * I) * 512 + 2 * J;
            *reinterpret_cast<float4*>(op) = top;
            *reinterpret_cast<float4*>(op + 512) = bot;
        }
    }
}

extern "C" void kernel_launch(void* const* d_in, const int* in_sizes, int n_in,
                              void* d_out, int out_size, void* d_ws, size_t ws_size,
                              hipStream_t stream) {
    const float* x  = (const float*)d_in[0];
    const float* dw = (const float*)d_in[1];
    const float* db = (const float*)d_in[2];
    const float* uw = (const float*)d_in[3];
    const float* ub = (const float*)d_in[4];
    float* outp = (float*)d_out;

    float* wsf = (float*)d_ws;
    float* wd  = wsf;            // 729 floats (pad to 768)
    float* wu  = wsf + 768;      // 1296 floats
    float* zp  = wsf + 2240;     // 16-float zero page (16B aligned)
    float* LL1 = wsf + 2304;                         // 25.2 MB
    float* y   = LL1 + (size_t)BB * 3 * 256 * 256;   // 18.9 MB

    k0_rearrange<<<dim3(1), dim3(256), 0, stream>>>(dw, uw, wd, wu, zp);
    k1_dwt_down<<<dim3(8192), dim3(64), 0, stream>>>(x, wd, db, zp, LL1, y);
    k2_up_idwt<<<dim3(BB * 64), dim3(256), 0, stream>>>(y, wu, ub, LL1, outp);
}